// Round 3
// baseline (1228028.418 us; speedup 1.0000x reference)
//
#include <hip/hip_runtime.h>

// B=256, T=1024, H=512, IN=OUT=2
// Phase 1: 16 batch-groups x 16 col-slices; wg(128thr)=(group,slice); each wave
// owns 16 h-cols x 3 gates, weights resident in regs. Per-step all-gather of h
// within a group. Runtime XCD-placement detection: if each XCD holds exactly
// 32 wgs, groups are remapped XCD-local and exchange runs through L2 (sc0);
// otherwise device-coherent sc1 fallback. Both paths identical math.

typedef short bf16x8 __attribute__((ext_vector_type(8)));
typedef float f32x4  __attribute__((ext_vector_type(4)));

__device__ __forceinline__ unsigned f2bf(float f) {
  unsigned u = __builtin_bit_cast(unsigned, f);
  return (u + 0x7fffu + ((u >> 16) & 1u)) >> 16;   // RTNE fp32->bf16
}

#define ALD(reg, off, suf) \
  asm volatile("global_load_dwordx4 %0, %1, off offset:" #off " " suf \
               : "=v"(reg) : "v"(ap))
#define PST(off, val, suf) \
  asm volatile("global_store_dword %0, %1, off offset:" #off " " suf \
               :: "v"(pp), "v"(val))

#define KSTEP(kt) \
  acc0 = __builtin_amdgcn_mfma_f32_16x16x32_bf16(a##kt, wf0[kt], acc0, 0, 0, 0); \
  acc1 = __builtin_amdgcn_mfma_f32_16x16x32_bf16(a##kt, wf1[kt], acc1, 0, 0, 0); \
  acc2 = __builtin_amdgcn_mfma_f32_16x16x32_bf16(a##kt, wf2[kt], acc2, 0, 0, 0);

template<bool FAST>
__device__ __forceinline__ void gru_loop(
    const float* __restrict__ V, const float* __restrict__ W_ih,
    const float* __restrict__ W_hh, const float* __restrict__ b_ih,
    const float* __restrict__ b_hh, const float* __restrict__ Wr,
    float* __restrict__ res_all, unsigned* __restrict__ hbuf,
    unsigned* __restrict__ flags, int g, int slice, int w, int lane)
{
  const int cl  = lane & 15;
  const int hi4 = lane >> 4;
  const int c   = slice * 32 + w * 16 + cl;

  const float wir0 = W_ih[c * 2 + 0],          wir1 = W_ih[c * 2 + 1];
  const float wiz0 = W_ih[(512 + c) * 2 + 0],  wiz1 = W_ih[(512 + c) * 2 + 1];
  const float win0 = W_ih[(1024 + c) * 2 + 0], win1 = W_ih[(1024 + c) * 2 + 1];
  const float bsr = b_ih[c] + b_hh[c];
  const float bsz = b_ih[512 + c] + b_hh[512 + c];
  const float bin = b_ih[1024 + c];
  const float bhn = b_hh[1024 + c];
  const float wr0 = Wr[c], wr1 = Wr[512 + c];

  // B-fragments: 3 gates x 16 k-tiles, resident
  bf16x8 wf0[16], wf1[16], wf2[16];
  {
    const int brow = slice * 32 + w * 16 + cl;
    #pragma unroll
    for (int gt = 0; gt < 3; ++gt) {
      const float* src = W_hh + ((size_t)(gt * 512 + brow)) * 512 + hi4 * 8;
      #pragma unroll
      for (int kt = 0; kt < 16; ++kt) {
        float4 x = *reinterpret_cast<const float4*>(src + kt * 32);
        float4 y = *reinterpret_cast<const float4*>(src + kt * 32 + 4);
        bf16x8 t;
        t[0] = (short)f2bf(x.x); t[1] = (short)f2bf(x.y);
        t[2] = (short)f2bf(x.z); t[3] = (short)f2bf(x.w);
        t[4] = (short)f2bf(y.x); t[5] = (short)f2bf(y.y);
        t[6] = (short)f2bf(y.z); t[7] = (short)f2bf(y.w);
        if (gt == 0) wf0[kt] = t; else if (gt == 1) wf1[kt] = t; else wf2[kt] = t;
      }
    }
  }

  const char* hb = (const char*)hbuf;
  const unsigned aoff = (unsigned)(g * 16 + cl) * 1024u + (unsigned)hi4 * 16u;
  const char* ap0 = hb + aoff;
  const char* ap1 = hb + 262144 + aoff;
  const unsigned pub_off = (unsigned)(g * 16 + hi4 * 4) * 1024u + (unsigned)(c >> 1) * 4u;
  char* pub0 = (char*)hbuf + pub_off;
  char* pub1 = (char*)hbuf + 262144 + pub_off;

  unsigned* myflag = flags + g * 64 + slice * 2 + w;      // packed: 32 flags/group in 2 lines
  const char* fp   = (const char*)(flags + g * 64 + (lane & 31));

  float h0 = 0.f, h1 = 0.f, h2 = 0.f, h3 = 0.f;

  // prefetch V for s=0
  float2 vcur[4];
  #pragma unroll
  for (int j = 0; j < 4; ++j) {
    const int rj = g * 16 + hi4 * 4 + j;
    vcur[j] = *reinterpret_cast<const float2*>(&V[(size_t)rj * 2048]);
  }

  for (int s = 0; s < 1024; ++s) {
    f32x4 acc0 = {0.f, 0.f, 0.f, 0.f};
    f32x4 acc1 = {0.f, 0.f, 0.f, 0.f};
    f32x4 acc2 = {0.f, 0.f, 0.f, 0.f};

    if (s > 0) {
      // ---- wait for all 32 producer-waves of this group @ step s ----
      int gd = 0;
      for (;;) {
        unsigned fv;
        if constexpr (FAST)
          asm volatile("global_load_dword %0, %1, off sc0\n\ts_waitcnt vmcnt(0)"
                       : "=v"(fv) : "v"(fp) : "memory");
        else
          asm volatile("global_load_dword %0, %1, off sc1\n\ts_waitcnt vmcnt(0)"
                       : "=v"(fv) : "v"(fp) : "memory");
        if (__ballot(fv >= (unsigned)s) == ~0ull) break;
        if (++gd > (1 << 14)) break;      // hang insurance -> fast wrong answer
        if constexpr (!FAST) __builtin_amdgcn_s_sleep(1);
      }
      __builtin_amdgcn_sched_barrier(0);

      // ---- load A-frags (h(s-1)) ----
      const char* ap = ((s - 1) & 1) ? ap1 : ap0;
      bf16x8 a0,a1,a2,a3,a4,a5,a6,a7,a8,a9,a10,a11,a12,a13,a14,a15;
      if constexpr (FAST) {
        ALD(a0,0,"sc0");   ALD(a1,64,"sc0");  ALD(a2,128,"sc0"); ALD(a3,192,"sc0");
        ALD(a4,256,"sc0"); ALD(a5,320,"sc0"); ALD(a6,384,"sc0"); ALD(a7,448,"sc0");
        ALD(a8,512,"sc0"); ALD(a9,576,"sc0"); ALD(a10,640,"sc0");ALD(a11,704,"sc0");
        ALD(a12,768,"sc0");ALD(a13,832,"sc0");ALD(a14,896,"sc0");ALD(a15,960,"sc0");
      } else {
        ALD(a0,0,"sc1");   ALD(a1,64,"sc1");  ALD(a2,128,"sc1"); ALD(a3,192,"sc1");
        ALD(a4,256,"sc1"); ALD(a5,320,"sc1"); ALD(a6,384,"sc1"); ALD(a7,448,"sc1");
        ALD(a8,512,"sc1"); ALD(a9,576,"sc1"); ALD(a10,640,"sc1");ALD(a11,704,"sc1");
        ALD(a12,768,"sc1");ALD(a13,832,"sc1");ALD(a14,896,"sc1");ALD(a15,960,"sc1");
      }
      asm volatile("s_waitcnt vmcnt(0)" ::: "memory");
      __builtin_amdgcn_sched_barrier(0);

      KSTEP(0)  KSTEP(1)  KSTEP(2)  KSTEP(3)
      KSTEP(4)  KSTEP(5)  KSTEP(6)  KSTEP(7)
      KSTEP(8)  KSTEP(9)  KSTEP(10) KSTEP(11)
      KSTEP(12) KSTEP(13) KSTEP(14) KSTEP(15)
    }

    // ---- pointwise GRU update ----
    float hn_[4];
    const float hprev[4] = {h0, h1, h2, h3};
    #pragma unroll
    for (int j = 0; j < 4; ++j) {
      const float2 vv = vcur[j];
      float pr = acc0[j] + bsr + wir0 * vv.x + wir1 * vv.y;
      float pz = acc1[j] + bsz + wiz0 * vv.x + wiz1 * vv.y;
      float rg = 1.f / (1.f + __expf(-pr));
      float zg = 1.f / (1.f + __expf(-pz));
      float pn = win0 * vv.x + win1 * vv.y + bin + rg * (acc2[j] + bhn);
      pn = fminf(fmaxf(pn, -30.f), 30.f);
      float e2 = __expf(2.f * pn);
      float tg = (e2 - 1.f) / (e2 + 1.f);
      hn_[j] = (1.f - zg) * tg + zg * hprev[j];
    }
    h0 = hn_[0]; h1 = hn_[1]; h2 = hn_[2]; h3 = hn_[3];

    // ---- publish h(s) ----
    unsigned pk0, pk1, pk2, pk3;
    {
      float o0 = __shfl_xor(hn_[0], 1), o1 = __shfl_xor(hn_[1], 1);
      float o2 = __shfl_xor(hn_[2], 1), o3 = __shfl_xor(hn_[3], 1);
      pk0 = f2bf(hn_[0]) | (f2bf(o0) << 16);
      pk1 = f2bf(hn_[1]) | (f2bf(o1) << 16);
      pk2 = f2bf(hn_[2]) | (f2bf(o2) << 16);
      pk3 = f2bf(hn_[3]) | (f2bf(o3) << 16);
    }
    if (!(cl & 1)) {
      char* pp = (s & 1) ? pub1 : pub0;
      if constexpr (FAST) {
        PST(0, pk0, "sc0"); PST(1024, pk1, "sc0");
        PST(2048, pk2, "sc0"); PST(3072, pk3, "sc0");
      } else {
        PST(0, pk0, "sc1"); PST(1024, pk1, "sc1");
        PST(2048, pk2, "sc1"); PST(3072, pk3, "sc1");
      }
    }
    // drain publish stores, then raise flag
    {
      unsigned sv = (unsigned)(s + 1);
      if constexpr (FAST)
        asm volatile("s_waitcnt vmcnt(0)\n\tglobal_store_dword %0, %1, off sc0"
                     :: "v"(myflag), "v"(sv) : "memory");
      else
        asm volatile("s_waitcnt vmcnt(0)\n\tglobal_store_dword %0, %1, off sc1"
                     :: "v"(myflag), "v"(sv) : "memory");
    }

    // ---- slack work (retires during next step's poll) ----
    float p0[4], p1[4];
    #pragma unroll
    for (int j = 0; j < 4; ++j) { p0[j] = wr0 * hn_[j]; p1[j] = wr1 * hn_[j]; }
    #pragma unroll
    for (int m = 1; m < 16; m <<= 1) {
      #pragma unroll
      for (int j = 0; j < 4; ++j) {
        p0[j] += __shfl_xor(p0[j], m);
        p1[j] += __shfl_xor(p1[j], m);
      }
    }
    if (cl == 0) {
      #pragma unroll
      for (int j = 0; j < 4; ++j) {
        const int rj = g * 16 + hi4 * 4 + j;
        atomicAdd(&res_all[((size_t)s * 256 + rj) * 2 + 0], p0[j]);
        atomicAdd(&res_all[((size_t)s * 256 + rj) * 2 + 1], p1[j]);
      }
    }
    const int sn = (s < 1023) ? (s + 1) : 1023;
    #pragma unroll
    for (int j = 0; j < 4; ++j) {
      const int rj = g * 16 + hi4 * 4 + j;
      vcur[j] = *reinterpret_cast<const float2*>(&V[(size_t)rj * 2048 + 2 * sn]);
    }
  }
}

__global__ void __launch_bounds__(128, 1) gru_phase1(
    const float* __restrict__ V, const float* __restrict__ W_ih,
    const float* __restrict__ W_hh, const float* __restrict__ b_ih,
    const float* __restrict__ b_hh, const float* __restrict__ Wr,
    float* __restrict__ res_all, unsigned* __restrict__ hbuf,
    unsigned* __restrict__ flags, unsigned* __restrict__ xcdarr,
    unsigned* __restrict__ ictr)
{
  const int tid = threadIdx.x;
  const int w = tid >> 6;
  const int lane = tid & 63;
  const int bid = blockIdx.x;

  unsigned xcd_raw;
  asm volatile("s_getreg_b32 %0, hwreg(HW_REG_XCC_ID)" : "=s"(xcd_raw));

  if (tid == 0) {
    __hip_atomic_store(&xcdarr[bid], (xcd_raw & 7u) | 0x100u,
                       __ATOMIC_RELAXED, __HIP_MEMORY_SCOPE_AGENT);
    __hip_atomic_fetch_add(ictr, 1u, __ATOMIC_RELEASE, __HIP_MEMORY_SCOPE_AGENT);
    int gd = 0;
    while (__hip_atomic_load(ictr, __ATOMIC_ACQUIRE, __HIP_MEMORY_SCOPE_AGENT) < 256u) {
      __builtin_amdgcn_s_sleep(4);
      if (++gd > (1 << 16)) break;   // hang insurance
    }
  }
  __syncthreads();

  // everyone reads the placement table, computes identical verdict
  const unsigned myraw = xcdarr[bid];
  const int myx = (int)(myraw & 7u);
  int rank = 0;
  int c0=0,c1=0,c2=0,c3=0,c4=0,c5=0,c6=0,c7=0;
  bool allw = (myraw >> 8) == 1u;
  for (int j = 0; j < 256; ++j) {
    const unsigned raw = xcdarr[j];
    allw = allw && ((raw >> 8) == 1u);
    const int x = (int)(raw & 7u);
    c0 += (x==0); c1 += (x==1); c2 += (x==2); c3 += (x==3);
    c4 += (x==4); c5 += (x==5); c6 += (x==6); c7 += (x==7);
    rank += ((x == myx) && (j < bid)) ? 1 : 0;
  }
  const bool ok = allw && c0==32 && c1==32 && c2==32 && c3==32 &&
                  c4==32 && c5==32 && c6==32 && c7==32;

  int g, slice;
  if (ok) { g = myx * 2 + (rank >> 4); slice = rank & 15; }
  else    { g = bid & 15;              slice = bid >> 4;  }

  if (ok)
    gru_loop<true >(V, W_ih, W_hh, b_ih, b_hh, Wr, res_all, hbuf, flags, g, slice, w, lane);
  else
    gru_loop<false>(V, W_ih, W_hh, b_ih, b_hh, Wr, res_all, hbuf, flags, g, slice, w, lane);
}

// ---------------- Phase 2: correction scan (one wave per batch row) ----------
__global__ void __launch_bounds__(256) corr_phase2(
    const float* __restrict__ X0,
    const float* __restrict__ V,
    const float* __restrict__ Wa1,
    const float* __restrict__ ba1,
    const float* __restrict__ Wa2,
    const float* __restrict__ ba2,
    const float* __restrict__ br,
    const float* __restrict__ res_all,
    float* __restrict__ out)
{
  const int tid = threadIdx.x;
  const int wv = tid >> 6;
  const int lane = tid & 63;
  const int b = blockIdx.x * 4 + wv;

  float w1[4][4], bb1[4], w20[4], w21[4];
  #pragma unroll
  for (int q = 0; q < 4; q++) {
    const int h = lane * 4 + q;
    #pragma unroll
    for (int c = 0; c < 4; c++) w1[q][c] = Wa1[h * 4 + c];
    bb1[q] = ba1[h];
    w20[q] = Wa2[h];
    w21[q] = Wa2[256 + h];
  }
  const float c20 = ba2[0], c21 = ba2[1];
  const float br0 = br[0], br1 = br[1];
  float x0 = X0[b * 2], x1 = X0[b * 2 + 1];

  for (int c = 0; c < 16; c++) {
    const int tl = c * 64 + lane;
    const float2 vvl = *reinterpret_cast<const float2*>(&V[(b * 1024 + tl) * 2]);
    const float2 rrl = *reinterpret_cast<const float2*>(&res_all[(tl * 256 + b) * 2]);
    float sx = 0.f, sy = 0.f;
    for (int k = 0; k < 64; k++) {
      const float v0 = __shfl(vvl.x, k);
      const float v1 = __shfl(vvl.y, k);
      const float r0 = __shfl(rrl.x, k) + br0;
      const float r1 = __shfl(rrl.y, k) + br1;
      float l0 = 0.f, l1 = 0.f;
      #pragma unroll
      for (int q = 0; q < 4; q++) {
        float hq = w1[q][0] * x0 + w1[q][1] * x1 + w1[q][2] * v0 + w1[q][3] * v1 + bb1[q];
        hq = fmaxf(hq, 0.f);
        l0 += w20[q] * hq;
        l1 += w21[q] * hq;
      }
      #pragma unroll
      for (int m = 1; m < 64; m <<= 1) {
        l0 += __shfl_xor(l0, m);
        l1 += __shfl_xor(l1, m);
      }
      l0 += c20; l1 += c21;
      const float mx = fmaxf(l0, l1);
      const float e0 = __expf(l0 - mx), e1 = __expf(l1 - mx);
      const float inv = 1.f / (e0 + e1);
      x0 += v0 + (e0 * inv) * r0;
      x1 += v1 + (e1 * inv) * r1;
      if (k == lane) { sx = x0; sy = x1; }
    }
    float2 o; o.x = sx; o.y = sy;
    *reinterpret_cast<float2*>(&out[(b * 1024 + c * 64 + lane) * 2]) = o;
  }
}

extern "C" void kernel_launch(void* const* d_in, const int* in_sizes, int n_in,
                              void* d_out, int out_size, void* d_ws, size_t ws_size,
                              hipStream_t stream) {
  const float* X0   = (const float*)d_in[0];
  const float* V    = (const float*)d_in[1];
  const float* W_ih = (const float*)d_in[2];
  const float* W_hh = (const float*)d_in[3];
  const float* b_ih = (const float*)d_in[4];
  const float* b_hh = (const float*)d_in[5];
  const float* Wa1  = (const float*)d_in[6];
  const float* ba1  = (const float*)d_in[7];
  const float* Wa2  = (const float*)d_in[8];
  const float* ba2  = (const float*)d_in[9];
  const float* Wr   = (const float*)d_in[10];
  const float* br   = (const float*)d_in[11];
  float* out = (float*)d_out;

  char* ws = (char*)d_ws;
  float*    res_all = (float*)ws;                                      // 2 MB
  unsigned* hbuf    = (unsigned*)(ws + 2*1024*1024);                   // 512 KB
  unsigned* flags   = (unsigned*)(ws + 2*1024*1024 + 512*1024);        // 32 KB
  unsigned* xcdarr  = (unsigned*)(ws + 2*1024*1024 + 512*1024 + 32*1024); // 1 KB
  unsigned* ictr    = (unsigned*)(ws + 2*1024*1024 + 512*1024 + 33*1024); // 4 B
  const size_t total = 2*1024*1024 + 512*1024 + 34*1024;
  hipMemsetAsync(d_ws, 0, total, stream);

  hipLaunchKernelGGL(gru_phase1, dim3(256), dim3(128), 0, stream,
                     V, W_ih, W_hh, b_ih, b_hh, Wr, res_all, hbuf, flags,
                     xcdarr, ictr);
  hipLaunchKernelGGL(corr_phase2, dim3(64), dim3(256), 0, stream,
                     X0, V, Wa1, ba1, Wa2, ba2, br, res_all, out);
}

// Round 4
// 7798.315 us; speedup vs baseline: 157.4736x; 157.4736x over previous
//
#include <hip/hip_runtime.h>

// B=256, T=1024, H=512, IN=OUT=2
// Phase 1: 16 batch-groups (16 rows) x 4 parts (128 h-cols). wg = 512 thr
// (8 waves) = one (group, part). Weights register-resident (192 VGPR/wave).
// h exchanged via seq-tagged 16B units, device-scope (sc1), double-buffered
// by step parity. No flags, no store-drain: consumers poll the data tags.

typedef short bf16x8 __attribute__((ext_vector_type(8)));
typedef float f32x4  __attribute__((ext_vector_type(4)));
typedef unsigned u32x4 __attribute__((ext_vector_type(4)));

__device__ __forceinline__ unsigned f2bf(float f) {
  unsigned u = __builtin_bit_cast(unsigned, f);
  return (u + 0x7fffu + ((u >> 16) & 1u)) >> 16;   // RTNE fp32->bf16
}

#define KSTEP(kt, areg) \
  acc0 = __builtin_amdgcn_mfma_f32_16x16x32_bf16(areg, wf0[kt], acc0, 0, 0, 0); \
  acc1 = __builtin_amdgcn_mfma_f32_16x16x32_bf16(areg, wf1[kt], acc1, 0, 0, 0); \
  acc2 = __builtin_amdgcn_mfma_f32_16x16x32_bf16(areg, wf2[kt], acc2, 0, 0, 0);

__global__ void __launch_bounds__(512) gru_phase1(
    const float* __restrict__ V, const float* __restrict__ W_ih,
    const float* __restrict__ W_hh, const float* __restrict__ b_ih,
    const float* __restrict__ b_hh, const float* __restrict__ Wr,
    float* __restrict__ res_all,     // [T][B][2] fp32, pre-zeroed
    char* __restrict__ hbuf)         // [2][16][4] blocks of 8KB tagged units
{
  const int tid  = threadIdx.x;
  const int w    = tid >> 6;         // wave 0..7
  const int lane = tid & 63;
  const int cl   = lane & 15;
  const int hi4  = lane >> 4;
  const int g    = blockIdx.x & 15;  // batch group (rows g*16..g*16+15)
  const int p    = blockIdx.x >> 4;  // col part (cols p*128..p*128+127)

  __shared__ short hs[2][16][512];   // 32KB, XOR-swizzled bf16, dbuf by parity
  char* lds = (char*)hs;

  const int c = p * 128 + w * 16 + cl;       // owned global h col

  // ---- pointwise constants ----
  const float wir0 = W_ih[c * 2 + 0],          wir1 = W_ih[c * 2 + 1];
  const float wiz0 = W_ih[(512 + c) * 2 + 0],  wiz1 = W_ih[(512 + c) * 2 + 1];
  const float win0 = W_ih[(1024 + c) * 2 + 0], win1 = W_ih[(1024 + c) * 2 + 1];
  const float bsr = b_ih[c] + b_hh[c];
  const float bsz = b_ih[512 + c] + b_hh[512 + c];
  const float bin = b_ih[1024 + c];
  const float bhn = b_hh[1024 + c];
  const float wr0 = Wr[c], wr1 = Wr[512 + c];

  // ---- B-fragments: 3 gates x 16 k-tiles, register-resident ----
  bf16x8 wf0[16], wf1[16], wf2[16];
  #pragma unroll
  for (int gt = 0; gt < 3; ++gt) {
    const float* src = W_hh + ((size_t)(gt * 512 + c)) * 512 + hi4 * 8;
    #pragma unroll
    for (int kt = 0; kt < 16; ++kt) {
      float4 x = *reinterpret_cast<const float4*>(src + kt * 32);
      float4 y = *reinterpret_cast<const float4*>(src + kt * 32 + 4);
      bf16x8 t;
      t[0] = (short)f2bf(x.x); t[1] = (short)f2bf(x.y);
      t[2] = (short)f2bf(x.z); t[3] = (short)f2bf(x.w);
      t[4] = (short)f2bf(y.x); t[5] = (short)f2bf(y.y);
      t[6] = (short)f2bf(y.z); t[7] = (short)f2bf(y.w);
      if (gt == 0) wf0[kt] = t; else if (gt == 1) wf1[kt] = t; else wf2[kt] = t;
    }
  }

  // zero LDS buffer 0 (h(-1) = 0)
  for (int i = tid; i < 4096; i += 512) ((unsigned*)lds)[i] = 0;
  __syncthreads();

  // ---- exchange addresses ----
  // block(slot,g,part) = 8KB of 512 units x 16B: unit = {dw0,dw1,tag,pad}
  // unit u: row = u>>5, cols (u&31)*4 .. +3 (within the 128-col part)
  // producer: lanes cl%4==0 store 4 units (rows hi4*4+j), unit col = (w*16+cl)/4
  char* pub_base = hbuf + (size_t)((g * 4 + p)) * 8192;           // + slot*524288
  const int urow = tid >> 5, ucol = tid & 31;                     // consumer unit
  const unsigned roff = (unsigned)(urow * 512 + ucol * 16);

  float h0 = 0.f, h1 = 0.f, h2 = 0.f, h3 = 0.f;

  // V prefetch for s=0 (rows hi4*4+j)
  float2 vcur[4];
  #pragma unroll
  for (int j = 0; j < 4; ++j)
    vcur[j] = *reinterpret_cast<const float2*>(&V[(size_t)(g * 16 + hi4 * 4 + j) * 2048]);

  for (int s = 0; s < 1024; ++s) {
    f32x4 acc0 = {0.f, 0.f, 0.f, 0.f};
    f32x4 acc1 = {0.f, 0.f, 0.f, 0.f};
    f32x4 acc2 = {0.f, 0.f, 0.f, 0.f};

    if (s > 0) {
      // ---- A-frags from LDS buf[s&1] (h(s-1)), swizzled, 4 kt per batch ----
      const char* ab = lds + (s & 1) * 16384 + cl * 1024;
      const unsigned sw = (unsigned)((cl & 7) << 4);
      #pragma unroll
      for (int kb = 0; kb < 4; ++kb) {
        bf16x8 a0 = *(const bf16x8*)(ab + (((kb * 4 + 0) * 64 + hi4 * 16) ^ sw));
        bf16x8 a1 = *(const bf16x8*)(ab + (((kb * 4 + 1) * 64 + hi4 * 16) ^ sw));
        bf16x8 a2 = *(const bf16x8*)(ab + (((kb * 4 + 2) * 64 + hi4 * 16) ^ sw));
        bf16x8 a3 = *(const bf16x8*)(ab + (((kb * 4 + 3) * 64 + hi4 * 16) ^ sw));
        KSTEP(kb * 4 + 0, a0) KSTEP(kb * 4 + 1, a1)
        KSTEP(kb * 4 + 2, a2) KSTEP(kb * 4 + 3, a3)
      }
    }

    // ---- pointwise GRU update: lane owns col c, rows hi4*4+{0..3} ----
    float hn_[4];
    const float hprev[4] = {h0, h1, h2, h3};
    #pragma unroll
    for (int j = 0; j < 4; ++j) {
      const float2 vv = vcur[j];
      float pr = acc0[j] + bsr + wir0 * vv.x + wir1 * vv.y;
      float pz = acc1[j] + bsz + wiz0 * vv.x + wiz1 * vv.y;
      float rg = 1.f / (1.f + __expf(-pr));
      float zg = 1.f / (1.f + __expf(-pz));
      float pn = win0 * vv.x + win1 * vv.y + bin + rg * (acc2[j] + bhn);
      pn = fminf(fmaxf(pn, -30.f), 30.f);
      float e2 = __expf(2.f * pn);
      float tg = (e2 - 1.f) / (e2 + 1.f);
      hn_[j] = (1.f - zg) * tg + zg * hprev[j];
    }
    h0 = hn_[0]; h1 = hn_[1]; h2 = hn_[2]; h3 = hn_[3];

    // ---- pack col pairs (even cl: cols c,c+1) ----
    unsigned pk[4];
    #pragma unroll
    for (int j = 0; j < 4; ++j) {
      float o = __shfl_xor(hn_[j], 1);
      pk[j] = f2bf(hn_[j]) | (f2bf(o) << 16);
    }

    // ---- own cols -> LDS buf[(s+1)&1] ----
    {
      char* wb = lds + ((s + 1) & 1) * 16384;
      if (!(cl & 1)) {
        const unsigned bc = (unsigned)(2 * c);
        #pragma unroll
        for (int j = 0; j < 4; ++j) {
          const unsigned row = (unsigned)(hi4 * 4 + j);
          *(unsigned*)(wb + row * 1024 + (bc ^ ((row & 7) << 4))) = pk[j];
        }
      }
    }

    // ---- publish tagged units (single dwordx4 each, sc1, no drain) ----
    {
      unsigned q[4];
      #pragma unroll
      for (int j = 0; j < 4; ++j) q[j] = __shfl_xor(pk[j], 2);
      if (!(cl & 3)) {
        char* blk = pub_base + (size_t)(s & 1) * 524288;
        const unsigned ucolb = (unsigned)((w * 16 + cl) >> 2) * 16u;
        #pragma unroll
        for (int j = 0; j < 4; ++j) {
          const unsigned row = (unsigned)(hi4 * 4 + j);
          u32x4 val; val.x = pk[j]; val.y = q[j];
          val.z = (unsigned)(s + 1); val.w = 0u;
          char* pp = blk + row * 512 + ucolb;
          asm volatile("global_store_dwordx4 %0, %1, off sc1"
                       :: "v"(pp), "v"(val) : "memory");
        }
      }
    }

    // ---- slack work: res partials + V prefetch (overlaps peers' publish) ----
    {
      float p0[4], p1[4];
      #pragma unroll
      for (int j = 0; j < 4; ++j) { p0[j] = wr0 * hn_[j]; p1[j] = wr1 * hn_[j]; }
      #pragma unroll
      for (int m = 1; m < 16; m <<= 1) {
        #pragma unroll
        for (int j = 0; j < 4; ++j) {
          p0[j] += __shfl_xor(p0[j], m);
          p1[j] += __shfl_xor(p1[j], m);
        }
      }
      if (cl == 0) {
        #pragma unroll
        for (int j = 0; j < 4; ++j) {
          const int rj = g * 16 + hi4 * 4 + j;
          atomicAdd(&res_all[((size_t)s * 256 + rj) * 2 + 0], p0[j]);
          atomicAdd(&res_all[((size_t)s * 256 + rj) * 2 + 1], p1[j]);
        }
      }
      const int sn = (s < 1023) ? (s + 1) : 1023;
      #pragma unroll
      for (int j = 0; j < 4; ++j)
        vcur[j] = *reinterpret_cast<const float2*>(
            &V[(size_t)(g * 16 + hi4 * 4 + j) * 2048 + 2 * sn]);
    }

    // ---- consume 3 remote parts' h(s): poll tags, write LDS buf[(s+1)&1] ----
    if (s < 1023) {
      char* wb = lds + ((s + 1) & 1) * 16384;
      const unsigned want = (unsigned)(s + 1);
      #pragma unroll
      for (int r = 0; r < 3; ++r) {
        const int rp = (p + r + 1) & 3;
        const char* src = hbuf + (size_t)(s & 1) * 524288 +
                          (size_t)(g * 4 + rp) * 8192 + roff;
        u32x4 u;
        int gd = 0;
        do {
          asm volatile("global_load_dwordx4 %0, %1, off sc1\n\ts_waitcnt vmcnt(0)"
                       : "=v"(u) : "v"(src) : "memory");
          if (u.z == want) break;
        } while (++gd < (1 << 18));   // hang insurance -> fast wrong answer
        const unsigned bc = (unsigned)(rp * 256 + ucol * 8);
        uint2 pay; pay.x = u.x; pay.y = u.y;
        *(uint2*)(wb + (unsigned)urow * 1024 + (bc ^ (((unsigned)urow & 7) << 4))) = pay;
      }
    }
    __syncthreads();
  }
}

// ---------------- Phase 2: correction scan (one wave per batch row) ----------
__global__ void __launch_bounds__(256) corr_phase2(
    const float* __restrict__ X0,
    const float* __restrict__ V,
    const float* __restrict__ Wa1,
    const float* __restrict__ ba1,
    const float* __restrict__ Wa2,
    const float* __restrict__ ba2,
    const float* __restrict__ br,
    const float* __restrict__ res_all,
    float* __restrict__ out)
{
  const int tid = threadIdx.x;
  const int wv = tid >> 6;
  const int lane = tid & 63;
  const int b = blockIdx.x * 4 + wv;

  float w1[4][4], bb1[4], w20[4], w21[4];
  #pragma unroll
  for (int q = 0; q < 4; q++) {
    const int h = lane * 4 + q;
    #pragma unroll
    for (int c = 0; c < 4; c++) w1[q][c] = Wa1[h * 4 + c];
    bb1[q] = ba1[h];
    w20[q] = Wa2[h];
    w21[q] = Wa2[256 + h];
  }
  const float c20 = ba2[0], c21 = ba2[1];
  const float br0 = br[0], br1 = br[1];
  float x0 = X0[b * 2], x1 = X0[b * 2 + 1];

  for (int c = 0; c < 16; c++) {
    const int tl = c * 64 + lane;
    const float2 vvl = *reinterpret_cast<const float2*>(&V[(b * 1024 + tl) * 2]);
    const float2 rrl = *reinterpret_cast<const float2*>(&res_all[(tl * 256 + b) * 2]);
    float sx = 0.f, sy = 0.f;
    for (int k = 0; k < 64; k++) {
      const float v0 = __shfl(vvl.x, k);
      const float v1 = __shfl(vvl.y, k);
      const float r0 = __shfl(rrl.x, k) + br0;
      const float r1 = __shfl(rrl.y, k) + br1;
      float l0 = 0.f, l1 = 0.f;
      #pragma unroll
      for (int q = 0; q < 4; q++) {
        float hq = w1[q][0] * x0 + w1[q][1] * x1 + w1[q][2] * v0 + w1[q][3] * v1 + bb1[q];
        hq = fmaxf(hq, 0.f);
        l0 += w20[q] * hq;
        l1 += w21[q] * hq;
      }
      #pragma unroll
      for (int m = 1; m < 64; m <<= 1) {
        l0 += __shfl_xor(l0, m);
        l1 += __shfl_xor(l1, m);
      }
      l0 += c20; l1 += c21;
      const float mx = fmaxf(l0, l1);
      const float e0 = __expf(l0 - mx), e1 = __expf(l1 - mx);
      const float inv = 1.f / (e0 + e1);
      x0 += v0 + (e0 * inv) * r0;
      x1 += v1 + (e1 * inv) * r1;
      if (k == lane) { sx = x0; sy = x1; }
    }
    float2 o; o.x = sx; o.y = sy;
    *reinterpret_cast<float2*>(&out[(b * 1024 + c * 64 + lane) * 2]) = o;
  }
}

extern "C" void kernel_launch(void* const* d_in, const int* in_sizes, int n_in,
                              void* d_out, int out_size, void* d_ws, size_t ws_size,
                              hipStream_t stream) {
  const float* X0   = (const float*)d_in[0];
  const float* V    = (const float*)d_in[1];
  const float* W_ih = (const float*)d_in[2];
  const float* W_hh = (const float*)d_in[3];
  const float* b_ih = (const float*)d_in[4];
  const float* b_hh = (const float*)d_in[5];
  const float* Wa1  = (const float*)d_in[6];
  const float* ba1  = (const float*)d_in[7];
  const float* Wa2  = (const float*)d_in[8];
  const float* ba2  = (const float*)d_in[9];
  const float* Wr   = (const float*)d_in[10];
  const float* br   = (const float*)d_in[11];
  float* out = (float*)d_out;

  char* ws = (char*)d_ws;
  float* res_all = (float*)ws;                    // 2 MB
  char*  hbuf    = ws + 2 * 1024 * 1024;          // 1 MB (2 slots x 512KB)
  const size_t total = 3 * 1024 * 1024;
  hipMemsetAsync(d_ws, 0, total, stream);

  hipLaunchKernelGGL(gru_phase1, dim3(64), dim3(512), 0, stream,
                     V, W_ih, W_hh, b_ih, b_hh, Wr, res_all, hbuf);
  hipLaunchKernelGGL(corr_phase2, dim3(64), dim3(256), 0, stream,
                     X0, V, Wa1, ba1, Wa2, ba2, br, res_all, out);
}